// Round 11
// baseline (34.843 us; speedup 1.0000x reference)
//
#include <hip/hip_runtime.h>
#include <cstdint>

#define DEVFN __device__ __forceinline__

struct U128 { unsigned long long lo, hi; };

// rotate right by s (1..127): bit q of result = bit (q+s)%128 of w
DEVFN U128 rotr128(U128 w, int s) {
    U128 r;
    if (s == 64) { r.lo = w.hi; r.hi = w.lo; return r; }
    if (s < 64) {
        r.lo = (w.lo >> s) | (w.hi << (64 - s));
        r.hi = (w.hi >> s) | (w.lo << (64 - s));
    } else {
        int t = s - 64;
        unsigned long long lo = w.hi, hi = w.lo;
        r.lo = (lo >> t) | (hi << (64 - t));
        r.hi = (hi >> t) | (lo << (64 - t));
    }
    return r;
}

// logical shift right by s (1..127)
DEVFN U128 shr128(U128 w, int s) {
    U128 r;
    if (s == 64) { r.lo = w.hi; r.hi = 0ull; return r; }
    if (s < 64) {
        r.lo = (w.lo >> s) | (w.hi << (64 - s));
        r.hi = w.hi >> s;
    } else {
        r.lo = w.hi >> (s - 64); r.hi = 0ull;
    }
    return r;
}

DEVFN int levoff(int r) { return r * 128 - (r * (r - 1)) / 2; }

// KB: W0 -> G3 reduction, perfectly balanced by level pairing.
// Pair p (0..63): levels r=p (128-p rows) and r'=127-p (p+1 rows), 129 rows total.
//   chunk0 (c2=0): level p rows j=0..64 (65 rows)            -> G3[p]
//   chunk1 (c2=1): level p rows j=65..127-p (63-p rows)      -> G3[128+p]
//                  + level 127-p rows j=0..p (p+1 rows)      -> G3[64+p]
// Block = (p, c2, hc): 512 blocks, each reads exactly 64-65 quarter-rows (1 KB each).
// Block 512 computes Sm[b][r] = 2*(r==0?pc:128-pc) - 128.
__global__ __launch_bounds__(256) void kB(const int* __restrict__ x,
                                          const int* __restrict__ masks,
                                          const float* __restrict__ W0,
                                          float* __restrict__ Sm,
                                          float* __restrict__ G3) {
    int bid = blockIdx.x;
    int tid = threadIdx.x;

    if (bid == 512) {
        int b = tid >> 2;        // 64 rows of x
        int rc = tid & 3;        // 4 chunks of 32 r's
        const int* xb = x + b * 128;
        U128 w; w.lo = 0ull; w.hi = 0ull;
        #pragma unroll
        for (int p = 0; p < 64; ++p) w.lo |= (unsigned long long)(xb[p] & 1) << p;
        #pragma unroll
        for (int p = 0; p < 64; ++p) w.hi |= (unsigned long long)(xb[64 + p] & 1) << p;
        int r0 = rc * 32;
        if (r0 & 32) { U128 t = rotr128(w, 32); w.lo ^= t.lo; w.hi ^= t.hi; }
        if (r0 & 64) { U128 t = rotr128(w, 64); w.lo ^= t.lo; w.hi ^= t.hi; }
        for (int rr = 0; rr < 32; ++rr) {
            int r = r0 + rr;
            int pc = __popcll(w.lo) + __popcll(w.hi);
            int sv = (r == 0) ? pc : (128 - pc);
            Sm[b * 128 + r] = (float)(2 * sv - 128);
            U128 t = rotr128(w, 1);
            w.lo ^= t.lo; w.hi ^= t.hi;
        }
        return;
    }

    int hc = bid & 3;            // quarter of h (256 floats)
    int c2 = (bid >> 2) & 1;     // chunk half
    int p  = bid >> 3;           // pair 0..63

    int cntA = c2 ? (63 - p) : 65;        // rows from level p
    int cntB = c2 ? (p + 1)  : 0;         // rows from level 127-p
    int L = cntA + cntB;                  // 64 or 65
    int jA0 = c2 ? 65 : 0;                // first j of range A

    int lane = tid & 63;
    int g    = tid >> 6;         // row-group (= wave) 0..3

    __shared__ unsigned long long mw[3][2];
    __shared__ float cG[65];
    __shared__ float4 partG0[4][64];
    __shared__ float4 partG1[4][64];

    if (tid < 128) {
        int half = tid >> 6;
        int lane_ = tid & 63;
        #pragma unroll
        for (int k = 0; k < 3; ++k) {
            unsigned long long bal = __ballot(masks[k * 128 + half * 64 + lane_] & 1);
            if (lane_ == 0) mw[k][half] = bal;
        }
    }
    __syncthreads();
    if (tid < L) {
        int r, j;
        if (tid < cntA) { r = p;       j = jA0 + tid; }
        else            { r = 127 - p; j = tid - cntA; }
        int c = 0;
        #pragma unroll
        for (int k = 0; k < 3; ++k) {
            U128 m; m.lo = mw[k][0]; m.hi = mw[k][1];
            #pragma unroll
            for (int s = 1; s <= 64; s <<= 1) {
                if (r & s) { U128 t = shr128(m, s); m.lo ^= t.lo; m.hi ^= t.hi; }
            }
            int bit = (j < 64) ? (int)((m.lo >> j) & 1) : (int)((m.hi >> (j - 64)) & 1);
            c += bit;
        }
        cG[tid] = (float)(2 - c) * (1.0f / 256.0f);
    }
    __syncthreads();

    const float* baseA = W0 + (size_t)(levoff(p) + jA0) * 1024 + hc * 256 + lane * 4;
    const float* baseB = W0 + (size_t)levoff(127 - p) * 1024 + hc * 256 + lane * 4;
    float4 aG0 = {0.f, 0.f, 0.f, 0.f}, aG1 = {0.f, 0.f, 0.f, 0.f};
    #pragma unroll 4
    for (int jj = g; jj < L; jj += 4) {       // jj wave-uniform
        bool inA = jj < cntA;
        const float* addr = inA ? (baseA + (size_t)jj * 1024)
                                : (baseB + (size_t)(jj - cntA) * 1024);
        float4 v = *(const float4*)addr;
        float cg = cG[jj];
        if (inA) { aG0.x += cg * v.x; aG0.y += cg * v.y; aG0.z += cg * v.z; aG0.w += cg * v.w; }
        else     { aG1.x += cg * v.x; aG1.y += cg * v.y; aG1.z += cg * v.z; aG1.w += cg * v.w; }
    }
    partG0[g][lane] = aG0;
    partG1[g][lane] = aG1;
    __syncthreads();

    if (tid < 64) {
        float4 s0 = partG0[0][tid], s1 = partG1[0][tid];
        #pragma unroll
        for (int gg = 1; gg < 4; ++gg) {
            float4 q0 = partG0[gg][tid], q1 = partG1[gg][tid];
            s0.x += q0.x; s0.y += q0.y; s0.z += q0.z; s0.w += q0.w;
            s1.x += q1.x; s1.y += q1.y; s1.z += q1.z; s1.w += q1.w;
        }
        int out0 = c2 ? (128 + p) : p;
        *(float4*)(G3 + (size_t)out0 * 1024 + hc * 256 + tid * 4) = s0;
        if (c2)
            *(float4*)(G3 + (size_t)(64 + p) * 1024 + hc * 256 + tid * 4) = s1;
    }
}

// kF: fused layer-1 + layer-2 split-K. 1-D grid of 512; kc = bid&15 so all 32
// blocks sharing a kc (same G3 columns + W1 rows) land on one XCD (bid%8).
// Phase A: h0[b][k] = relu(b0[k] + sum_row Sm[b][r(row)] * G3[row][k]),
//          r(row) = row<64 ? row : row<128 ? 191-row : row-128.
// Phase B: z1part[b][kc][hc-slice] = h0 . W1tile
__global__ __launch_bounds__(256) void kF(const float* __restrict__ G3,
                                          const float* __restrict__ Sm,
                                          const float* __restrict__ b0,
                                          const float* __restrict__ W1,
                                          float* __restrict__ z1part) {
    int bid = blockIdx.x;
    int kc = bid & 15;            // 0..15  (64 k each)  -> XCD = kc&7
    int hc = (bid >> 4) & 7;      // 0..7   (128 h-cols each)
    int bs = bid >> 7;            // 0..3   (16 b each)
    int tid = threadIdx.x;

    __shared__ float W1sh[64][128];   // 32 KB
    __shared__ float Ssh[16][128];    // 8 KB (pre-shifted S - 128)
    __shared__ float h0sh[16][64];    // 4 KB

    #pragma unroll
    for (int t = 0; t < 32; ++t) {
        int idx = tid + t * 256;      // 0..8191
        int kk = idx >> 7, hcl = idx & 127;
        W1sh[kk][hcl] = W1[(kc * 64 + kk) * 1024 + hc * 128 + hcl];
    }
    #pragma unroll
    for (int t = 0; t < 8; ++t) {
        int idx = tid + t * 256;      // 0..2047
        int bl = idx >> 7, r = idx & 127;
        Ssh[bl][r] = Sm[(bs * 16 + bl) * 128 + r];
    }
    __syncthreads();

    // ---- Phase A: h0 sub-tile ----
    {
        int k = tid & 63;
        int bg = tid >> 6;
        const float* g2p = G3 + kc * 64 + k;
        float acc[4] = {0.f, 0.f, 0.f, 0.f};
        #pragma unroll 8
        for (int row = 0; row < 192; ++row) {
            float gv = g2p[row * 1024];
            int r = row < 64 ? row : (row < 128 ? 191 - row : row - 128);
            #pragma unroll
            for (int bb = 0; bb < 4; ++bb)
                acc[bb] += Ssh[bg * 4 + bb][r] * gv;
        }
        float base = b0[kc * 64 + k];
        #pragma unroll
        for (int bb = 0; bb < 4; ++bb)
            h0sh[bg * 4 + bb][k] = fmaxf(base + acc[bb], 0.f);
    }
    __syncthreads();

    // ---- Phase B: z1part tile = h0sh (16x64) . W1sh (64x128) ----
    {
        int hcol = tid & 127;
        int bg2 = tid >> 7;
        float acc2[8];
        #pragma unroll
        for (int i = 0; i < 8; ++i) acc2[i] = 0.f;
        #pragma unroll 4
        for (int kk = 0; kk < 64; ++kk) {
            float w = W1sh[kk][hcol];
            #pragma unroll
            for (int bb = 0; bb < 8; ++bb)
                acc2[bb] += h0sh[bg2 * 8 + bb][kk] * w;
        }
        #pragma unroll
        for (int bb = 0; bb < 8; ++bb) {
            int b = bs * 16 + bg2 * 8 + bb;
            z1part[((size_t)b * 16 + kc) * 1024 + hc * 128 + hcol] = acc2[bb];
        }
    }
}

// kE: out[b] = sum_h relu(b1[h] + sum_kc z1part[b][kc][h]) * Wo[h] + bo
// z1part laid out [b][kc][h] -> each block reads one contiguous 64 KB span.
__global__ __launch_bounds__(1024) void kE(const float* __restrict__ z1part,
                                           const float* __restrict__ b1,
                                           const float* __restrict__ Wo,
                                           const float* __restrict__ bo,
                                           float* __restrict__ out) {
    int b = blockIdx.x;
    int h = threadIdx.x;
    const float* zp = z1part + (size_t)b * 16384 + h;
    float z = b1[h];
    #pragma unroll
    for (int kc = 0; kc < 16; ++kc) z += zp[kc * 1024];
    float acc = fmaxf(z, 0.f) * Wo[h];
    #pragma unroll
    for (int off = 32; off >= 1; off >>= 1) acc += __shfl_down(acc, off);
    __shared__ float red[16];
    if ((h & 63) == 0) red[h >> 6] = acc;
    __syncthreads();
    if (h == 0) {
        float s = bo[0];
        #pragma unroll
        for (int i = 0; i < 16; ++i) s += red[i];
        out[b] = s;
    }
}

extern "C" void kernel_launch(void* const* d_in, const int* in_sizes, int n_in,
                              void* d_out, int out_size, void* d_ws, size_t ws_size,
                              hipStream_t stream) {
    const int*   x     = (const int*)d_in[0];    // (64,128) 0/1
    const int*   masks = (const int*)d_in[1];    // (3,128) 0/1
    const float* W0    = (const float*)d_in[2];  // (8256,1024)
    const float* b0    = (const float*)d_in[3];  // (1024)
    const float* W1    = (const float*)d_in[4];  // (1024,1024)
    const float* b1    = (const float*)d_in[5];  // (1024)
    const float* Wo    = (const float*)d_in[6];  // (1024,1)
    const float* bo    = (const float*)d_in[7];  // (1)
    float* out = (float*)d_out;                  // (64,1)

    char* ws = (char*)d_ws;
    float* Sm     = (float*)(ws);                      // 64*128*4      = 32 KB
    float* G3     = (float*)(ws + (32u  << 10));       // 192*1024*4    = 768 KB
    float* z1part = (float*)(ws + (800u << 10));       // 64*16*1024*4  = 4 MB

    kB<<<513, 256, 0, stream>>>(x, masks, W0, Sm, G3);
    kF<<<512, 256, 0, stream>>>(G3, Sm, b0, W1, z1part);
    kE<<<64, 1024, 0, stream>>>(z1part, b1, Wo, bo, out);
}